// Round 10
// baseline (326.283 us; speedup 1.0000x reference)
//
#include <hip/hip_runtime.h>

#define NPTS   8192
#define CCH    32
#define LDIM   64
#define ODIM   128
#define KNN    16
#define QPB    64                  // queries per block (16 per wave = MFMA tile rows)
#define TILEC  128                 // candidates per LDS tile
#define NTIL   (NPTS / TILEC)      // 64
#define NBLK   ((4 * NPTS) / QPB)  // 512 blocks
#define SCAP   56                  // survivor capacity per query (analysis: worst ~40)
#define CSTRIDE 80                 // bytes per candidate row in LDS (32 fp16 + pad)
#define MARGIN 0.75f               // >= 2*eps bound for fp16 distance error

typedef _Float16 half8   __attribute__((ext_vector_type(8)));
typedef _Float16 half4v  __attribute__((ext_vector_type(4)));
typedef float    float4v __attribute__((ext_vector_type(4)));

// Prologue: squared norms of all 32768 points into d_ws (exact fp32).
__global__ void sq_kernel(const float* __restrict__ x, float* __restrict__ sqg) {
    int i = blockIdx.x * 256 + threadIdx.x;
    const float4* p = (const float4*)(x + (size_t)i * CCH);
    float s = 0.f;
    #pragma unroll
    for (int k = 0; k < 8; ++k) {
        float4 v = p[k];
        s += v.x * v.x + v.y * v.y + v.z * v.z + v.w * v.w;
    }
    sqg[i] = s;
}

// LDS layout (phase overlays):
//  scan:   s0 @0 (10240) | s1 @10240 (10240) | sq0 @20480 (512) | sq1 @20992 (512)
//          slist/t32 @21504 (14336) | scnt @35840 (256) | tq @36096 (256)
//  pass3:  skeys @0 (14336) | kn @14336 (4096)          (stream bufs dead)
//  epilog: pl @0 (8448) | hh @18432 (16640)             (skeys/slist dead)
#define LDS_BYTES 36352
#define OFF_S1   10240
#define OFF_SQ0  20480
#define OFF_SQ1  20992
#define OFF_SL   21504
#define OFF_SC   35840
#define OFF_TQ   36096
#define OFF_KN   14336
#define OFF_HH   18432

// launch_bounds(256,4): 4 blocks/CU (LDS 36.3KB*4 = 145KB <= 160KB; VGPR cap 128,
// r9 used 84 at cap 256 -> fits). r9's (256,2) left the kernel latency-bound at
// 2 waves/SIMD with every pipe under 35% busy.
__global__ __launch_bounds__(256, 4)
void graph_layer_kernel(const float* __restrict__ x,
                        const float* __restrict__ sqg,
                        const float* __restrict__ Wl,
                        const float* __restrict__ bl,
                        const float* __restrict__ Wc,
                        const float* __restrict__ bc,
                        float* __restrict__ out)
{
    __shared__ __align__(16) char smem[LDS_BYTES];
    char*  s0    = smem;
    char*  s1    = smem + OFF_S1;
    float* sq0   = (float*)(smem + OFF_SQ0);
    float* sq1   = (float*)(smem + OFF_SQ1);
    int*   slist = (int*)(smem + OFF_SL);
    float* t32   = (float*)(smem + OFF_SL);    // overlay, consumed before slist writes
    int*   scnt  = (int*)(smem + OFF_SC);
    float* tq    = (float*)(smem + OFF_TQ);
    float* skeys = (float*)smem;               // pass-3 overlay
    int*   kn    = (int*)(smem + OFF_KN);
    float* pl    = (float*)smem;               // epilogue overlay
    float* hh    = (float*)(smem + OFF_HH);

    const int tid  = threadIdx.x;
    const int lane = tid & 63;
    const int w    = tid >> 6;
    const int col  = lane & 15;                // candidate column / A-frag row
    const int quad = lane >> 4;
    const float INF = __builtin_inff();

    const int qb0 = blockIdx.x * QPB;
    const int b   = qb0 >> 13;
    const int qbl = qb0 & (NPTS - 1);
    const float* xb  = x   + (size_t)(b << 13) * CCH;
    const float* sqb = sqg + (b << 13);

    // ---- A-fragment: wave's 16 queries in fp16; A[m=col][k=quad*8+j] ----
    half8 qh;
    {
        const float* qr = x + (size_t)(qb0 + w * 16 + col) * CCH + quad * 8;
        float4 f0 = *(const float4*)qr;
        float4 f1 = *(const float4*)(qr + 4);
        qh[0]=(_Float16)f0.x; qh[1]=(_Float16)f0.y; qh[2]=(_Float16)f0.z; qh[3]=(_Float16)f0.w;
        qh[4]=(_Float16)f1.x; qh[5]=(_Float16)f1.y; qh[6]=(_Float16)f1.z; qh[7]=(_Float16)f1.w;
    }

    float4 r0, r1, r2, r3; float sqv = 0.f;
    auto stage_load = [&](int T) {
        const float4* g = (const float4*)(xb + (size_t)T * TILEC * CCH);
        r0 = g[tid]; r1 = g[tid + 256]; r2 = g[tid + 512]; r3 = g[tid + 768];
        if (tid < TILEC) sqv = sqb[T * TILEC + tid];
    };
    auto stage_write = [&](char* buf, float* sqs) {
        auto wr = [&](int ch, float4 r) {
            int cd = ch >> 3, kq = ch & 7;
            half4v h;
            h[0]=(_Float16)r.x; h[1]=(_Float16)r.y; h[2]=(_Float16)r.z; h[3]=(_Float16)r.w;
            *(half4v*)(buf + cd * CSTRIDE + kq * 8) = h;
        };
        wr(tid, r0); wr(tid+256, r1); wr(tid+512, r2); wr(tid+768, r3);
        if (tid < TILEC) sqs[tid] = sqv;
    };

    // ================= PASS 1: branch-free per-lane top-2 per query ==========
    float m1[4] = {INF, INF, INF, INF};
    float m2[4] = {INF, INF, INF, INF};

    stage_load(0); stage_write(s0, sq0);
    __syncthreads();
    #pragma unroll 1
    for (int T = 0; T < NTIL; ++T) {
        if (T + 1 < NTIL) stage_load(T + 1);
        const char*  cb = (T & 1) ? s1 : s0;
        const float* sv = (T & 1) ? sq1 : sq0;
        #pragma unroll
        for (int st = 0; st < 8; ++st) {
            half8 bh = *(const half8*)(cb + (size_t)(st * 16 + col) * CSTRIDE + quad * 16);
            float sc = sv[st * 16 + col];
            float4v acc = __builtin_amdgcn_mfma_f32_16x16x32_f16(
                qh, bh, (float4v){0.f, 0.f, 0.f, 0.f}, 0, 0, 0);
            #pragma unroll
            for (int j = 0; j < 4; ++j) {
                float key = fmaf(-2.f, acc[j], sc);
                float lo = fminf(key, m1[j]);
                float hi = fmaxf(key, m1[j]);
                m1[j] = lo;
                m2[j] = fminf(m2[j], hi);
            }
        }
        if (T + 1 < NTIL) stage_write(((T + 1) & 1) ? s1 : s0,
                                      ((T + 1) & 1) ? sq1 : sq0);
        __syncthreads();
    }

    // ---- per-query threshold: 16th smallest of the 32-value union ----
    #pragma unroll
    for (int j = 0; j < 4; ++j) {
        int qq = w * 16 + quad * 4 + j;
        t32[qq * 32 + col * 2 + 0] = m1[j];
        t32[qq * 32 + col * 2 + 1] = m2[j];
    }
    __syncthreads();
    if (tid < QPB) {
        float kd[KNN];
        #pragma unroll
        for (int p = 0; p < KNN; ++p) kd[p] = INF;
        for (int i = 0; i < 32; ++i) {
            float ck = t32[tid * 32 + i];
            if (ck < kd[KNN - 1]) {
                #pragma unroll
                for (int p = 0; p < KNN; ++p) {
                    bool sw = ck < kd[p];
                    float nk = sw ? ck : kd[p];
                    ck = sw ? kd[p] : ck;
                    kd[p] = nk;
                }
            }
        }
        tq[tid] = kd[KNN - 1];
        scnt[tid] = 0;
    }
    __syncthreads();
    float T2[4];
    #pragma unroll
    for (int j = 0; j < 4; ++j) T2[j] = tq[w * 16 + quad * 4 + j] + MARGIN;

    // ================= PASS 2: rescan, atomic survivor append ==========
    stage_load(0); stage_write(s0, sq0);
    __syncthreads();
    #pragma unroll 1
    for (int T = 0; T < NTIL; ++T) {
        if (T + 1 < NTIL) stage_load(T + 1);
        const char*  cb = (T & 1) ? s1 : s0;
        const float* sv = (T & 1) ? sq1 : sq0;
        #pragma unroll
        for (int st = 0; st < 8; ++st) {
            half8 bh = *(const half8*)(cb + (size_t)(st * 16 + col) * CSTRIDE + quad * 16);
            float sc = sv[st * 16 + col];
            float4v acc = __builtin_amdgcn_mfma_f32_16x16x32_f16(
                qh, bh, (float4v){0.f, 0.f, 0.f, 0.f}, 0, 0, 0);
            #pragma unroll
            for (int j = 0; j < 4; ++j) {
                float key = fmaf(-2.f, acc[j], sc);
                if (key < T2[j]) {
                    int qq = w * 16 + quad * 4 + j;
                    int slot = atomicAdd(&scnt[qq], 1);
                    if (slot < SCAP)
                        slist[qq * SCAP + slot] = T * TILEC + st * 16 + col;
                }
            }
        }
        if (T + 1 < NTIL) stage_write(((T + 1) & 1) ? s1 : s0,
                                      ((T + 1) & 1) ? sq1 : sq0);
        __syncthreads();
    }

    // ================= PASS 3: exact fp32 re-check of survivors ==========
    {
        int qq = tid & 63, sb = tid >> 6;
        int n = scnt[qq]; if (n > SCAP) n = SCAP;
        const float4* xi4 = (const float4*)(xb + (size_t)(qbl + qq) * CCH);
        for (int s = sb; s < n; s += 4) {
            int jdx = slist[qq * SCAP + s];
            const float4* xj = (const float4*)(xb + (size_t)jdx * CCH);
            float a0 = 0.f, a1 = 0.f, a2 = 0.f, a3 = 0.f;
            #pragma unroll
            for (int k = 0; k < 8; ++k) {
                float4 cv = xj[k], qv = xi4[k];
                a0 = fmaf(cv.x, qv.x, a0); a1 = fmaf(cv.y, qv.y, a1);
                a2 = fmaf(cv.z, qv.z, a2); a3 = fmaf(cv.w, qv.w, a3);
            }
            float dot = (a0 + a1) + (a2 + a3);
            skeys[qq * SCAP + s] = fmaf(-2.f, dot, sqb[jdx]);
        }
    }
    __syncthreads();
    if (tid < QPB) {      // exact (key, idx) top-16; slist is UNORDERED -> full lex compare
        int n = scnt[tid]; if (n > SCAP) n = SCAP;
        float kd[KNN]; int ki[KNN];
        #pragma unroll
        for (int p = 0; p < KNN; ++p) { kd[p] = INF; ki[p] = 0x7fffffff; }
        for (int s = 0; s < n; ++s) {
            float ck = skeys[tid * SCAP + s];
            int   cj = slist[tid * SCAP + s];
            if (ck < kd[KNN-1] || (ck == kd[KNN-1] && cj < ki[KNN-1])) {
                #pragma unroll
                for (int p = 0; p < KNN; ++p) {
                    bool sw = (ck < kd[p]) || (ck == kd[p] && cj < ki[p]);
                    float nk = sw ? ck : kd[p];
                    int   nj = sw ? cj : ki[p];
                    ck = sw ? kd[p] : ck;
                    cj = sw ? ki[p] : cj;
                    kd[p] = nk; ki[p] = nj;
                }
            }
        }
        #pragma unroll
        for (int r = 0; r < KNN; ++r) kn[tid * KNN + r] = ki[r];
    }
    __syncthreads();

    // ================= epilogue: gather + max-pool + MLP ==========
    {
        int q = tid >> 2, part = tid & 3;
        float4 m0 = make_float4(-INF, -INF, -INF, -INF);
        float4 mm1 = m0;
        #pragma unroll
        for (int k = 0; k < KNN; ++k) {
            int j = kn[q * KNN + k];
            const float4* r = (const float4*)(xb + (size_t)j * CCH + part * 8);
            float4 v0 = r[0], v1 = r[1];
            m0.x = fmaxf(m0.x, v0.x); m0.y = fmaxf(m0.y, v0.y);
            m0.z = fmaxf(m0.z, v0.z); m0.w = fmaxf(m0.w, v0.w);
            mm1.x = fmaxf(mm1.x, v1.x); mm1.y = fmaxf(mm1.y, v1.y);
            mm1.z = fmaxf(mm1.z, v1.z); mm1.w = fmaxf(mm1.w, v1.w);
        }
        float* d = pl + q * 33 + part * 8;
        d[0] = m0.x; d[1] = m0.y; d[2] = m0.z; d[3] = m0.w;
        d[4] = mm1.x; d[5] = mm1.y; d[6] = mm1.z; d[7] = mm1.w;
    }
    __syncthreads();
    {
        int l = tid & 63, qg2 = tid >> 6;
        #pragma unroll 1
        for (int qq = qg2; qq < QPB; qq += 4) {
            float acc = bl[l];
            #pragma unroll
            for (int c = 0; c < CCH; ++c)
                acc = fmaf(pl[qq * 33 + c], Wl[c * LDIM + l], acc);
            hh[qq * 65 + l] = acc;
        }
    }
    __syncthreads();
    {
        int o = tid & 127, qh2 = tid >> 7;
        #pragma unroll 1
        for (int qq = qh2; qq < QPB; qq += 2) {
            float acc = bc[o];
            #pragma unroll
            for (int l = 0; l < LDIM; ++l)
                acc = fmaf(hh[qq * 65 + l], Wc[l * ODIM + o], acc);
            out[(size_t)(qb0 + qq) * ODIM + o] = fmaxf(acc, 0.f);
        }
    }
}

extern "C" void kernel_launch(void* const* d_in, const int* in_sizes, int n_in,
                              void* d_out, int out_size, void* d_ws, size_t ws_size,
                              hipStream_t stream) {
    const float* x  = (const float*)d_in[0];
    const float* Wl = (const float*)d_in[1];
    const float* bl = (const float*)d_in[2];
    const float* Wc = (const float*)d_in[3];
    const float* bc = (const float*)d_in[4];
    float* out = (float*)d_out;
    float* sqf = (float*)d_ws;                 // 32768 floats = 128 KB
    (void)in_sizes; (void)n_in; (void)out_size; (void)ws_size;

    hipLaunchKernelGGL(sq_kernel, dim3((4 * NPTS) / 256), dim3(256), 0, stream, x, sqf);
    hipLaunchKernelGGL(graph_layer_kernel, dim3(NBLK), dim3(256), 0, stream,
                       x, sqf, Wl, bl, Wc, bc, out);
}